// Round 8
// baseline (148.412 us; speedup 1.0000x reference)
//
#include <hip/hip_runtime.h>
#include <math.h>

#define BB 4096
#define FF 64
#define RR 16   // F / RED
#define DD 512
#define KK 8

__global__ __launch_bounds__(256) void ca1d_fused(
    const float* __restrict__ x,   // [B,F,D]
    const float* __restrict__ w1,  // [R,F]
    const float* __restrict__ b1,  // [R]
    const float* __restrict__ w2,  // [F,R]
    const float* __restrict__ b2,  // [F]
    float* __restrict__ out)       // [B,K,D]
{
    const int b    = blockIdx.x;
    const int tid  = threadIdx.x;
    const int lane = tid & 63;
    const int wave = tid >> 6;   // 0..3

    __shared__ double s_pooled[FF];
    __shared__ double s_h[RR];
    __shared__ double s_z[FF];
    __shared__ int    s_idx[KK];

    const float* xb = x + (size_t)b * FF * DD;

    // ---- Stage 1: pooled[f] = mean_D x[b,f,:]  (f64 accumulation)
    for (int f = wave; f < FF; f += 4) {
        const float4* row = reinterpret_cast<const float4*>(xb + f * DD);
        float4 v0 = row[lane];        // coalesced: 64 lanes x 16B
        float4 v1 = row[lane + 64];
        double s = ((double)v0.x + (double)v0.y) + ((double)v0.z + (double)v0.w)
                 + ((double)v1.x + (double)v1.y) + ((double)v1.z + (double)v1.w);
        #pragma unroll
        for (int off = 32; off > 0; off >>= 1)
            s += __shfl_xor(s, off, 64);
        if (lane == 0) s_pooled[f] = s * (1.0 / DD);
    }
    __syncthreads();

    // ---- Stage 2: h[r] = relu(dot(pooled, w1[r,:]) + b1[r])   (f64 exact)
    if (tid < RR) {
        double acc = (double)b1[tid];
        const float* wr = w1 + tid * FF;
        #pragma unroll
        for (int f = 0; f < FF; ++f) acc += s_pooled[f] * (double)wr[f];
        s_h[tid] = acc > 0.0 ? acc : 0.0;
    }
    __syncthreads();

    // ---- Stage 3: z[f] = dot(h, w2[f,:]) + b2[f]   (f64 exact)
    if (tid < FF) {
        double acc = (double)b2[tid];
        const float* wf = w2 + tid * RR;
        #pragma unroll
        for (int r = 0; r < RR; ++r) acc += s_h[r] * (double)wf[r];
        s_z[tid] = acc;
    }
    __syncthreads();

    // ---- Stage 4: top-K on the np-style THREE-ROUNDING sigmoid chain:
    //   e   = f32(exp(-z))          (np.exp: SVML/glibc ~ correctly-rounded f32)
    //   den = f32(1.0f + e)
    //   w   = f32(1.0f / den)
    // Each op individually f32-rounded, exactly as numpy executes
    // 1/(1+np.exp(-z)). This can differ by 1 ulp from the single-rounded
    // sigmoid (R3) — the remaining untested lever. Ties -> LOWER index
    // (R7 proved higher-index ties are wrong).
    if (wave == 0) {
        float e   = (float)exp(-s_z[lane]);   // f64 exp -> f32 round == CR f32 exp
        float den = 1.0f + e;                 // f32 round
        float v   = 1.0f / den;               // f32 round
        #pragma unroll
        for (int k = 0; k < KK; ++k) {
            float bv = v;
            int   bi = lane;
            #pragma unroll
            for (int off = 32; off > 0; off >>= 1) {
                float ov = __shfl_xor(bv, off, 64);
                int   oi = __shfl_xor(bi, off, 64);
                if (ov > bv || (ov == bv && oi < bi)) { bv = ov; bi = oi; }
            }
            // butterfly: all lanes agree on (bv, bi)
            if (lane == 0) s_idx[k] = bi;
            if (lane == bi) v = -INFINITY;  // remove selected
        }
    }
    __syncthreads();

    // ---- Stage 5: gather 8 selected rows -> out[b, k, :]
    float4* ob = reinterpret_cast<float4*>(out + (size_t)b * KK * DD);
    #pragma unroll
    for (int i = tid; i < KK * DD / 4; i += 256) {   // 1024 float4, 4 per thread
        int k = i >> 7;        // / 128
        int c = i & 127;
        const float4* src = reinterpret_cast<const float4*>(xb + (size_t)s_idx[k] * DD);
        ob[i] = src[c];
    }
}

extern "C" void kernel_launch(void* const* d_in, const int* in_sizes, int n_in,
                              void* d_out, int out_size, void* d_ws, size_t ws_size,
                              hipStream_t stream) {
    const float* x  = (const float*)d_in[0];
    const float* w1 = (const float*)d_in[1];
    const float* b1 = (const float*)d_in[2];
    const float* w2 = (const float*)d_in[3];
    const float* b2 = (const float*)d_in[4];
    float* out = (float*)d_out;

    ca1d_fused<<<BB, 256, 0, stream>>>(x, w1, b1, w2, b2, out);
}

// Round 9
// 114.599 us; speedup vs baseline: 1.2951x; 1.2951x over previous
//
#include <hip/hip_runtime.h>
#include <math.h>

#define BB 4096
#define FF 64
#define RR 16   // F / RED
#define DD 512
#define KK 8

typedef float f32x4 __attribute__((ext_vector_type(4)));

__global__ __launch_bounds__(256) void ca1d_fused(
    const float* __restrict__ x,   // [B,F,D]
    const float* __restrict__ w1,  // [R,F]
    const float* __restrict__ b1,  // [R]
    const float* __restrict__ w2,  // [F,R]
    const float* __restrict__ b2,  // [F]
    float* __restrict__ out)       // [B,K,D]
{
    const int b    = blockIdx.x;
    const int tid  = threadIdx.x;
    const int lane = tid & 63;
    const int wave = tid >> 6;   // 0..3

    __shared__ double s_pooled[FF];
    __shared__ double s_h[RR];
    __shared__ double s_z[FF];
    __shared__ float  s_w[FF];
    __shared__ int    s_idx[KK];

    const float* xb = x + (size_t)b * FF * DD;

    // ---- Stage 1: pooled[f] = mean_D x[b,f,:]  (f64 accumulation)
    // BIT-FROZEN math (passed R8): per-lane pair-tree, then xor 32,16,8,4,2,1.
    // unroll 4 -> 8 float4 loads + 4 independent shuffle chains in flight
    // (in-order wave issue otherwise stalls next loads behind the DS chain).
    #pragma unroll 4
    for (int f = wave; f < FF; f += 4) {
        const float4* row = reinterpret_cast<const float4*>(xb + f * DD);
        float4 v0 = row[lane];        // coalesced: 64 lanes x 16B
        float4 v1 = row[lane + 64];
        double s = ((double)v0.x + (double)v0.y) + ((double)v0.z + (double)v0.w)
                 + ((double)v1.x + (double)v1.y) + ((double)v1.z + (double)v1.w);
        #pragma unroll
        for (int off = 32; off > 0; off >>= 1)
            s += __shfl_xor(s, off, 64);
        if (lane == 0) s_pooled[f] = s * (1.0 / DD);
    }
    __syncthreads();

    // ---- Stage 2: h[r] = relu(dot(pooled, w1[r,:]) + b1[r])   (f64 exact, BIT-FROZEN)
    if (tid < RR) {
        double acc = (double)b1[tid];
        const float* wr = w1 + tid * FF;
        #pragma unroll
        for (int f = 0; f < FF; ++f) acc += s_pooled[f] * (double)wr[f];
        s_h[tid] = acc > 0.0 ? acc : 0.0;
    }
    __syncthreads();

    // ---- Stage 3: z[f] = dot(h, w2[f,:]) + b2[f]   (f64 exact, BIT-FROZEN)
    if (tid < FF) {
        double acc = (double)b2[tid];
        const float* wf = w2 + tid * RR;
        #pragma unroll
        for (int r = 0; r < RR; ++r) acc += s_h[r] * (double)wf[r];
        s_z[tid] = acc;
    }
    __syncthreads();

    // ---- Stage 4: top-K on the np-style THREE-ROUNDING sigmoid chain
    // (BIT-FROZEN values):  e = f32(exp(-z)); den = f32(1+e); w = f32(1/den).
    // Selection: rank-based top-k, provably equivalent to the R8 butterfly
    // (total order: descending w, exact ties -> lower index), but 64
    // independent pipelined LDS broadcast reads instead of a 48-deep
    // serial DS shuffle chain.
    if (wave == 0) {
        float e   = (float)exp(-s_z[lane]);   // f64 exp -> f32 round
        float den = 1.0f + e;                 // f32 round
        float v   = 1.0f / den;               // f32 round
        s_w[lane] = v;                        // same-wave DS ordering is in-order
        int rank = 0;
        #pragma unroll
        for (int j = 0; j < FF; ++j) {
            float wj = s_w[j];                // uniform-address broadcast (conflict-free)
            rank += (wj > v || (wj == v && j < lane)) ? 1 : 0;
        }
        if (rank < KK) s_idx[rank] = lane;
    }
    __syncthreads();

    // ---- Stage 5: gather 8 selected rows -> out[b, k, :]
    // nontemporal stores: out is never re-read; keep L2 for x rows.
    f32x4* ob = (f32x4*)(out + (size_t)b * KK * DD);
    #pragma unroll
    for (int i = tid; i < KK * DD / 4; i += 256) {   // 1024 float4, 4 per thread
        int k = i >> 7;        // / 128
        int c = i & 127;
        const f32x4* src = (const f32x4*)(xb + (size_t)s_idx[k] * DD);
        __builtin_nontemporal_store(src[c], ob + i);
    }
}

extern "C" void kernel_launch(void* const* d_in, const int* in_sizes, int n_in,
                              void* d_out, int out_size, void* d_ws, size_t ws_size,
                              hipStream_t stream) {
    const float* x  = (const float*)d_in[0];
    const float* w1 = (const float*)d_in[1];
    const float* b1 = (const float*)d_in[2];
    const float* w2 = (const float*)d_in[3];
    const float* b2 = (const float*)d_in[4];
    float* out = (float*)d_out;

    ca1d_fused<<<BB, 256, 0, stream>>>(x, w1, b1, w2, b2, out);
}